// Round 19
// baseline (191.707 us; speedup 1.0000x reference)
//
#include <hip/hip_runtime.h>

#define NITER 10
#define WRK 250    // worker blocks (<=256 CUs), 16 waves each, 1 block/CU
#define GRID 251   // workers + 1 dedicated sweeper block
#define HB 32      // histogram blocks
#define CAP_H 96   // per-wave LDS capacity for a half edge slice
#define NBARS (3 + 2 * NITER - 1)  // 22 barrier generations

// ---------------- helpers ----------------

__device__ __forceinline__ uint32_t aload(const uint32_t* p) {
  return __hip_atomic_load(p, __ATOMIC_RELAXED, __HIP_MEMORY_SCOPE_AGENT);
}
__device__ __forceinline__ void astore(uint32_t* p, uint32_t v) {
  __hip_atomic_store(p, v, __ATOMIC_RELAXED, __HIP_MEMORY_SCOPE_AGENT);
}
__device__ __forceinline__ void astoreb(unsigned char* p, unsigned char v) {
  __hip_atomic_store(p, v, __ATOMIC_RELAXED, __HIP_MEMORY_SCOPE_AGENT);
}
__device__ __forceinline__ float bf2f_lo(uint32_t v) { return __uint_as_float(v << 16); }
__device__ __forceinline__ float bf2f_hi(uint32_t v) { return __uint_as_float(v & 0xFFFF0000u); }
__device__ __forceinline__ uint32_t f2bf_bits(float f) {  // RNE, top 16 bits
  uint32_t b = __float_as_uint(f);
  b += 0x7FFFu + ((b >> 16) & 1u);
  return b >> 16;
}
__device__ __forceinline__ uint32_t pack_bf16x2(float lo, float hi) {
  return f2bf_bits(lo) | (f2bf_bits(hi) << 16);
}

// ---------------- worker-side barrier (byte arrival + paced poll) ----------------
// Arrival: one sc1 BYTE store to slot[bid] (250 slots pack into 2 LLC lines;
// byte-enable write-through merges concurrent stores to the same dword).
// Release: thread 0 polls the single gen word (s_sleep(1)-paced, round-17
// proven). Monotonic targets 1..NBARS fit a byte; host memset zeroes state.
// vmcnt(0) before arrival drains sc1 write-through payload stores to LLC, so
// gen>=target implies all payloads visible.
__device__ __forceinline__ void gbar(unsigned char* slotb, uint32_t* gen, uint32_t target) {
  asm volatile("s_waitcnt vmcnt(0)" ::: "memory");
  __syncthreads();
  if (threadIdx.x == 0) {
    astoreb(&slotb[blockIdx.x], (unsigned char)target);
    while (aload(gen) < target) __builtin_amdgcn_s_sleep(1);
  }
  __syncthreads();
  asm volatile("" ::: "memory");
}

// ---------------- gathers ----------------
// L2M=true: plain loads (L2-cacheable; safe because each rotating message
// buffer is written once per launch, read only after the barrier, values are
// replay-invariant; dispatch boundary invalidates L2 - proven rounds 1-3).
// L2M=false: sc1 loads (LLC), single-buffer fallback (round-14 proven).

template <bool L2M>
__device__ __forceinline__ uint32_t mload(const uint32_t* p) {
  if constexpr (L2M) return *p;
  else return aload(p);
}

template <bool L2M>
__device__ __forceinline__ void gq_lds(const uint32_t* __restrict__ se, int len,
                                       const uint32_t* buf, int lane, float& o0, float& o1) {
  float a0[8], a1[8];
#pragma unroll
  for (int j = 0; j < 8; ++j) { a0[j] = 0.f; a1[j] = 0.f; }
#pragma unroll 2
  for (int p = 0; p < len; p += 8) {
    uint32_t e[8];
#pragma unroll
    for (int j = 0; j < 8; ++j) e[j] = se[p + j];
    uint32_t v[8];
#pragma unroll
    for (int j = 0; j < 8; ++j) v[j] = mload<L2M>(&buf[((e[j] & 0xFFFFu) << 6) + lane]);
#pragma unroll
    for (int j = 0; j < 8; ++j) {
      float wj = __uint_as_float(e[j] & 0xFFFF0000u);
      a0[j] = fmaf(wj, bf2f_lo(v[j]), a0[j]);
      a1[j] = fmaf(wj, bf2f_hi(v[j]), a1[j]);
    }
  }
  o0 = ((a0[0] + a0[1]) + (a0[2] + a0[3])) + ((a0[4] + a0[5]) + (a0[6] + a0[7]));
  o1 = ((a1[0] + a1[1]) + (a1[2] + a1[3])) + ((a1[4] + a1[5]) + (a1[6] + a1[7]));
}

template <bool L2M>
__device__ __forceinline__ void gq_glb(const uint32_t* __restrict__ ed, int len,
                                       const uint32_t* buf, int lane, float& o0, float& o1) {
  float a0[8], a1[8];
#pragma unroll
  for (int j = 0; j < 8; ++j) { a0[j] = 0.f; a1[j] = 0.f; }
#pragma unroll 2
  for (int p = 0; p < len; p += 8) {
    uint32_t e[8], v[8];
#pragma unroll
    for (int j = 0; j < 8; ++j) {
      bool ok = (p + j) < len;
      e[j] = ok ? aload(&ed[p + j]) : 0u;
      v[j] = ok ? mload<L2M>(&buf[((e[j] & 0xFFFFu) << 6) + lane]) : 0u;
    }
#pragma unroll
    for (int j = 0; j < 8; ++j) {
      float wj = __uint_as_float(e[j] & 0xFFFF0000u);
      a0[j] = fmaf(wj, bf2f_lo(v[j]), a0[j]);
      a1[j] = fmaf(wj, bf2f_hi(v[j]), a1[j]);
    }
  }
  o0 = ((a0[0] + a0[1]) + (a0[2] + a0[3])) + ((a0[4] + a0[5]) + (a0[6] + a0[7]));
  o1 = ((a1[0] + a1[1]) + (a1[2] + a1[3])) + ((a1[4] + a1[5]) + (a1[6] + a1[7]));
}

// ---------------- the single fused persistent kernel ----------------
// Block WRK (250) = dedicated sweeper: wave 0 checks all 250 byte-slots with
// ONE dword load per lane (2 LLC lines total) per sweep round (s_sleep-paced),
// publishes gen; waves 1..15 exit at start. Workers: A hist -> B scans ->
// C scatter + inits -> 19-barrier loop. Pruning: edgeS keeps mask[src]!=0;
// edgeT keeps mask[src]!=0 && mask[tgt]!=0. 2 waves per active node,
// round-robin dealt.

template <bool L2M>
__global__ __launch_bounds__(1024, 4) void pc_all(
    const float* __restrict__ x, float* __restrict__ out,
    const int* __restrict__ src, const int* __restrict__ tgt,
    const float* __restrict__ w, const float* __restrict__ mask,
    int* __restrict__ partS, int* __restrict__ partT,
    int* __restrict__ offS, int* __restrict__ offT,
    int* __restrict__ curS, int* __restrict__ curT,
    int* __restrict__ actv, int* __restrict__ nactg,
    uint32_t* __restrict__ edgeS, uint32_t* __restrict__ edgeT,
    uint32_t* fx32, uint32_t* err32, uint32_t* barbuf, int E, int N) {
  __shared__ int h[4096];
  __shared__ uint32_t sE[2][16][CAP_H];
  __shared__ float2 psum[8][64];
  unsigned char* slotb = (unsigned char*)barbuf;  // 256 bytes = 64 dwords = 2 lines
  uint32_t* gen = barbuf + 64;                    // byte 256: own line

  const int bid = blockIdx.x, tid = threadIdx.x;
  const int wid = tid >> 6, lane = tid & 63;

  // ---- dedicated sweeper block: private loop, no __syncthreads, then exit ----
  if (bid == WRK) {
    if (wid == 0) {
      const uint32_t* sw = barbuf;  // slots as 64 dwords, lane i owns dword i
      for (uint32_t t = 1; t <= (uint32_t)NBARS; ++t) {
        for (;;) {
          uint32_t v = aload(&sw[lane]);
          bool ok = true;
#pragma unroll
          for (int j = 0; j < 4; ++j) {
            int b = lane * 4 + j;
            uint32_t byte = (v >> (8 * j)) & 0xFFu;
            ok &= (b >= WRK) || (byte >= t);
          }
          if (__all(ok)) break;
          __builtin_amdgcn_s_sleep(1);
        }
        if (lane == 0) astore(gen, t);
      }
    }
    return;
  }

  const int row = N * 64;
  const int fstr = L2M ? row : 0;
  const int estr = L2M ? row : 0;

  // ---- A: pruned partial histograms ----
  if (bid < HB) {
    for (int i = tid; i < 2 * N; i += 1024) h[i] = 0;
    __syncthreads();
    const int chunk = (E + HB - 1) / HB;
    const int base = bid * chunk;
    const int end = min(base + chunk, E);
    for (int e = base + tid; e < end; e += 1024) {
      int s = src[e], t = tgt[e];
      if (mask[s] != 0.f) {
        atomicAdd(&h[s], 1);
        if (mask[t] != 0.f) atomicAdd(&h[N + t], 1);
      }
    }
    __syncthreads();
    for (int i = tid; i < N; i += 1024) {
      astore((uint32_t*)&partS[bid * 2048 + i], (uint32_t)h[i]);
      astore((uint32_t*)&partT[bid * 2048 + i], (uint32_t)h[N + i]);
    }
  }
  gbar(slotb, gen, 1);

  // ---- B: exclusive scans (block 0 -> S, 1 -> T, 2 -> active compaction) ----
  if (bid < 3) {
    int* tsum = h;
    int v2[2];
    int s = 0;
#pragma unroll
    for (int i2 = 0; i2 < 2; ++i2) {
      int idx = tid * 2 + i2;
      int c = 0;
      if (idx < N) {
        if (bid == 2) {
          c = (mask[idx] != 0.f) ? 1 : 0;
        } else {
          const uint32_t* part = (const uint32_t*)(bid ? partT : partS);
          for (int k = 0; k < HB; ++k) c += (int)aload(&part[k * 2048 + idx]);
        }
      }
      v2[i2] = s;
      s += c;
    }
    __syncthreads();
    tsum[tid] = s;
    __syncthreads();
    for (int d = 1; d < 1024; d <<= 1) {
      int t = (tid >= d) ? tsum[tid - d] : 0;
      __syncthreads();
      tsum[tid] += t;
      __syncthreads();
    }
    int tbase = tsum[tid] - s;
    if (bid == 2) {
#pragma unroll
      for (int i2 = 0; i2 < 2; ++i2) {
        int idx = tid * 2 + i2;
        if (idx < N && mask[idx] != 0.f)
          astore((uint32_t*)&actv[tbase + v2[i2]], (uint32_t)idx);
      }
      if (tid == 1023) astore((uint32_t*)nactg, (uint32_t)tsum[1023]);
    } else {
      int* off = bid ? offT : offS;
      int* cur = bid ? curT : curS;
#pragma unroll
      for (int i2 = 0; i2 < 2; ++i2) {
        int idx = tid * 2 + i2;
        if (idx < N) {
          int o = tbase + v2[i2];
          astore((uint32_t*)&off[idx], (uint32_t)o);
          astore((uint32_t*)&cur[idx], (uint32_t)o);
        } else if (idx == N) {
          astore((uint32_t*)&off[idx], (uint32_t)(tbase + v2[i2]));
        }
      }
    }
  }
  gbar(slotb, gen, 2);

  // ---- C: pruned scatter + active setup + fx(0) + masked init ----
  {
    const int chunk = (E + WRK - 1) / WRK;
    const int base = bid * chunk;
    const int end = min(base + chunk, E);
    for (int e = base + tid; e < end; e += 1024) {
      int s = src[e], t = tgt[e];
      if (mask[s] != 0.f) {
        uint32_t wb = __float_as_uint(w[e]);
        wb = (wb + 0x7FFFu + ((wb >> 16) & 1u)) & 0xFFFF0000u;  // bf16 bits, high half
        int p = atomicAdd(&curS[s], 1);
        astore(&edgeS[p], (uint32_t)t | wb);  // mu pass: src gathers fx[tgt]
        if (mask[t] != 0.f) {
          int q = atomicAdd(&curT[t], 1);
          astore(&edgeT[q], (uint32_t)s | wb);  // agg pass: tgt gathers err[src]
        }
      }
    }
  }

  const int ps = wid >> 1, sub = wid & 1;
  const int nact = (int)aload((const uint32_t*)nactg);
  const int p = ps * WRK + bid;
  const bool act = (p < nact);
  int n = 0, i = 0, aS = 0, qlS = 0, qpS = 0, aT = 0, qlT = 0, qpT = 0;
  bool fS = true, fT = true;
  float m = 0.f, x0 = 0.f, x1 = 0.f, fx0 = 0.f, fx1 = 0.f, e0 = 0.f, e1 = 0.f;

  if (act) {
    n = (int)aload((const uint32_t*)&actv[p]);
    i = (n << 6) + lane;
    const uint32_t* offSu = (const uint32_t*)offS;
    const uint32_t* offTu = (const uint32_t*)offT;
    const int s0 = (int)aload(&offSu[n]), degS = (int)aload(&offSu[n + 1]) - s0;
    const int t0 = (int)aload(&offTu[n]), degT = (int)aload(&offTu[n + 1]) - t0;
    aS = s0 + ((degS * sub) >> 1); qlS = (s0 + ((degS * (sub + 1)) >> 1)) - aS;
    aT = t0 + ((degT * sub) >> 1); qlT = (t0 + ((degT * (sub + 1)) >> 1)) - aT;
    qpS = (qlS + 7) & ~7; qpT = (qlT + 7) & ~7;
    fS = (qpS <= CAP_H); fT = (qpT <= CAP_H);
    if (sub == 0) {  // primary owns node state; lane l owns batch (2l, 2l+1)
      m = mask[n];
      x0 = x[(2 * lane) * N + n];
      x1 = x[(2 * lane + 1) * N + n];
      fx0 = tanhf(x0);
      fx1 = tanhf(x1);
      astore(&fx32[i], pack_bf16x2(fx0, fx1));  // F_0
    }
  }
  // masked nodes: constant fx -> every F_k buffer; x never changes -> out = x
  for (int g = bid * 1024 + tid; g < row; g += WRK * 1024) {
    int nn = g >> 6;
    if (mask[nn] == 0.f) {
      int l = g & 63;
      uint32_t pv = pack_bf16x2(tanhf(x[(2 * l) * N + nn]), tanhf(x[(2 * l + 1) * N + nn]));
      if constexpr (L2M) {
        for (int k = 0; k < NITER; ++k) astore(&fx32[(size_t)k * row + g], pv);
      } else {
        astore(&fx32[g], pv);
      }
    }
  }
  for (int g = bid * 1024 + tid; g < N * 128; g += WRK * 1024) {
    int b = g / N, nn = g - b * N;
    if (mask[nn] == 0.f) out[g] = x[g];
  }
  gbar(slotb, gen, 3);

  // ---- stage this wave's half-slices into LDS (wave-private) ----
  if (act) {
    if (fS)
      for (int k = lane; k < qpS; k += 64) sE[0][wid][k] = (k < qlS) ? aload(&edgeS[aS + k]) : 0u;
    if (fT)
      for (int k = lane; k < qpT; k += 64) sE[1][wid][k] = (k < qlT) ? aload(&edgeT[aT + k]) : 0u;
  }

  // ---- main loop ----
  uint32_t g = 3;
  for (int it = 0; it < NITER; ++it) {
    const uint32_t* Fk = fx32 + (size_t)it * fstr;
    uint32_t* Ek = err32 + (size_t)it * estr;
    // phase 1: mu half-gather over F_it; combine; publish E_it
    float p0 = 0.f, p1 = 0.f;
    if (act) {
      if (fS) gq_lds<L2M>(&sE[0][wid][0], qpS, Fk, lane, p0, p1);
      else    gq_glb<L2M>(edgeS + aS, qlS, Fk, lane, p0, p1);
      if (sub) psum[ps][lane] = make_float2(p0, p1);
    }
    __syncthreads();
    if (act && sub == 0) {
      float2 q = psum[ps][lane];
      e0 = (x0 - (p0 + q.x)) * m;
      e1 = (x1 - (p1 + q.y)) * m;
      astore(&Ek[i], pack_bf16x2(e0, e1));
    }
    gbar(slotb, gen, ++g);

    // phase 2: agg half-gather over E_it; combine; update x; publish F_{it+1}
    if (act) {
      if (fT) gq_lds<L2M>(&sE[1][wid][0], qpT, Ek, lane, p0, p1);
      else    gq_glb<L2M>(edgeT + aT, qlT, Ek, lane, p0, p1);
      if (sub) psum[ps][lane] = make_float2(p0, p1);
    }
    __syncthreads();
    if (act && sub == 0) {
      float2 q = psum[ps][lane];
      const float ag0 = p0 + q.x, ag1 = p1 + q.y;
      const float dx0 = e0 - (1.f - fx0 * fx0) * ag0;
      const float dx1 = e1 - (1.f - fx1 * fx1) * ag1;
      x0 -= 0.5f * dx0 * m;
      x1 -= 0.5f * dx1 * m;
      fx0 = tanhf(x0);
      fx1 = tanhf(x1);
      if (it < NITER - 1) astore(&fx32[(size_t)(it + 1) * fstr + i], pack_bf16x2(fx0, fx1));
    }
    if (it < NITER - 1) gbar(slotb, gen, ++g);
  }

  if (act && sub == 0) {
    out[(2 * lane) * N + n] = x0;
    out[(2 * lane + 1) * N + n] = x1;
  }
}

// ---------------- host ----------------

extern "C" void kernel_launch(void* const* d_in, const int* in_sizes, int n_in,
                              void* d_out, int out_size, void* d_ws, size_t ws_size,
                              hipStream_t stream) {
  const float* x = (const float*)d_in[0];
  const int* ei = (const int*)d_in[1];
  const float* w = (const float*)d_in[2];
  const float* mask = (const float*)d_in[3];
  int E = in_sizes[2];  // 131072
  int N = in_sizes[3];  // 2000
  const int* src = ei;
  const int* tgt = ei + E;
  float* out = (float*)d_out;

  size_t off = 0;
  auto alloc = [&](size_t bytes) -> void* {
    off = (off + 255) & ~(size_t)255;
    void* p = (char*)d_ws + off;
    off += bytes;
    return p;
  };
  uint32_t* edgeS = (uint32_t*)alloc((size_t)E * 4);
  uint32_t* edgeT = (uint32_t*)alloc((size_t)E * 4);
  int* partS = (int*)alloc((size_t)HB * 2048 * 4);
  int* partT = (int*)alloc((size_t)HB * 2048 * 4);
  int* offS = (int*)alloc(2048 * 4);
  int* offT = (int*)alloc(2048 * 4);
  int* curS = (int*)alloc(2048 * 4);
  int* curT = (int*)alloc(2048 * 4);
  int* actv = (int*)alloc(2048 * 4);
  int* nactg = (int*)alloc(64 * 4);
  uint32_t* barbuf = (uint32_t*)alloc(512 * 4);  // 64 slot-dwords + gen + pad

  const size_t row = (size_t)N * 64 * 4;  // bytes per message buffer
  bool l2mode = (off + 2 * (size_t)NITER * row + 512) <= ws_size;
  uint32_t* fx32, *err32;
  if (l2mode) {
    fx32 = (uint32_t*)alloc((size_t)NITER * row);
    err32 = (uint32_t*)alloc((size_t)NITER * row);
  } else {
    fx32 = (uint32_t*)alloc(row);
    err32 = (uint32_t*)alloc(row);
  }

  // barrier state must be zero at the start of every replay (monotonic targets)
  hipMemsetAsync(barbuf, 0, 512 * 4, stream);

  if (l2mode) {
    pc_all<true><<<GRID, 1024, 0, stream>>>(x, out, src, tgt, w, mask, partS, partT, offS, offT,
                                            curS, curT, actv, nactg, edgeS, edgeT, fx32, err32,
                                            barbuf, E, N);
  } else {
    pc_all<false><<<GRID, 1024, 0, stream>>>(x, out, src, tgt, w, mask, partS, partT, offS, offT,
                                             curS, curT, actv, nactg, edgeS, edgeT, fx32, err32,
                                             barbuf, E, N);
  }
}

// Round 20
// 153.573 us; speedup vs baseline: 1.2483x; 1.2483x over previous
//
#include <hip/hip_runtime.h>

#define NITER 10
#define WRK 250    // worker blocks (<=256 CUs), 16 waves each, 1 block/CU
#define GRID 251   // workers + 1 dedicated sweeper block
#define HB 32      // histogram blocks
#define CAP_H 96   // per-wave LDS capacity for a half edge slice
#define NBARS (3 + 2 * NITER - 1)  // 22 barrier generations

// ---------------- helpers ----------------

__device__ __forceinline__ uint32_t aload(const uint32_t* p) {
  return __hip_atomic_load(p, __ATOMIC_RELAXED, __HIP_MEMORY_SCOPE_AGENT);
}
__device__ __forceinline__ void astore(uint32_t* p, uint32_t v) {
  __hip_atomic_store(p, v, __ATOMIC_RELAXED, __HIP_MEMORY_SCOPE_AGENT);
}
__device__ __forceinline__ float bf2f_lo(uint32_t v) { return __uint_as_float(v << 16); }
__device__ __forceinline__ float bf2f_hi(uint32_t v) { return __uint_as_float(v & 0xFFFF0000u); }
__device__ __forceinline__ uint32_t f2bf_bits(float f) {  // RNE, top 16 bits
  uint32_t b = __float_as_uint(f);
  b += 0x7FFFu + ((b >> 16) & 1u);
  return b >> 16;
}
__device__ __forceinline__ uint32_t pack_bf16x2(float lo, float hi) {
  return f2bf_bits(lo) | (f2bf_bits(hi) << 16);
}

// ---------------- worker-side barrier (arrive + paced poll) ----------------
// Round-17 proven optimum. Arrival: one sc1 store to the block's OWN dword
// slot (stride 1: arrivals spread over 32 LLC lines -> no line serialization).
// Release: thread 0 polls the single gen word, s_sleep(1)-paced. Monotonic
// targets; host memset zeroes slots+gen every replay. vmcnt(0) before arrival
// drains sc1 write-through payload stores to LLC, so gen>=target implies all
// payloads visible.
__device__ __forceinline__ void gbar(uint32_t* slots, uint32_t* gen, uint32_t target) {
  asm volatile("s_waitcnt vmcnt(0)" ::: "memory");
  __syncthreads();
  if (threadIdx.x == 0) {
    astore(&slots[blockIdx.x], target);
    while (aload(gen) < target) __builtin_amdgcn_s_sleep(1);
  }
  __syncthreads();
  asm volatile("" ::: "memory");
}

// ---------------- gathers ----------------
// L2M=true: plain loads (L2-cacheable; safe because each rotating message
// buffer is written once per launch, read only after the barrier, values are
// replay-invariant; dispatch boundary invalidates L2 - proven rounds 1-3).
// L2M=false: sc1 loads (LLC), single-buffer fallback (round-14 proven).

template <bool L2M>
__device__ __forceinline__ uint32_t mload(const uint32_t* p) {
  if constexpr (L2M) return *p;
  else return aload(p);
}

template <bool L2M>
__device__ __forceinline__ void gq_lds(const uint32_t* __restrict__ se, int len,
                                       const uint32_t* buf, int lane, float& o0, float& o1) {
  float a0[8], a1[8];
#pragma unroll
  for (int j = 0; j < 8; ++j) { a0[j] = 0.f; a1[j] = 0.f; }
#pragma unroll 2
  for (int p = 0; p < len; p += 8) {
    uint32_t e[8];
#pragma unroll
    for (int j = 0; j < 8; ++j) e[j] = se[p + j];
    uint32_t v[8];
#pragma unroll
    for (int j = 0; j < 8; ++j) v[j] = mload<L2M>(&buf[((e[j] & 0xFFFFu) << 6) + lane]);
#pragma unroll
    for (int j = 0; j < 8; ++j) {
      float wj = __uint_as_float(e[j] & 0xFFFF0000u);
      a0[j] = fmaf(wj, bf2f_lo(v[j]), a0[j]);
      a1[j] = fmaf(wj, bf2f_hi(v[j]), a1[j]);
    }
  }
  o0 = ((a0[0] + a0[1]) + (a0[2] + a0[3])) + ((a0[4] + a0[5]) + (a0[6] + a0[7]));
  o1 = ((a1[0] + a1[1]) + (a1[2] + a1[3])) + ((a1[4] + a1[5]) + (a1[6] + a1[7]));
}

template <bool L2M>
__device__ __forceinline__ void gq_glb(const uint32_t* __restrict__ ed, int len,
                                       const uint32_t* buf, int lane, float& o0, float& o1) {
  float a0[8], a1[8];
#pragma unroll
  for (int j = 0; j < 8; ++j) { a0[j] = 0.f; a1[j] = 0.f; }
#pragma unroll 2
  for (int p = 0; p < len; p += 8) {
    uint32_t e[8], v[8];
#pragma unroll
    for (int j = 0; j < 8; ++j) {
      bool ok = (p + j) < len;
      e[j] = ok ? aload(&ed[p + j]) : 0u;
      v[j] = ok ? mload<L2M>(&buf[((e[j] & 0xFFFFu) << 6) + lane]) : 0u;
    }
#pragma unroll
    for (int j = 0; j < 8; ++j) {
      float wj = __uint_as_float(e[j] & 0xFFFF0000u);
      a0[j] = fmaf(wj, bf2f_lo(v[j]), a0[j]);
      a1[j] = fmaf(wj, bf2f_hi(v[j]), a1[j]);
    }
  }
  o0 = ((a0[0] + a0[1]) + (a0[2] + a0[3])) + ((a0[4] + a0[5]) + (a0[6] + a0[7]));
  o1 = ((a1[0] + a1[1]) + (a1[2] + a1[3])) + ((a1[4] + a1[5]) + (a1[6] + a1[7]));
}

// ---------------- the single fused persistent kernel ----------------
// Block WRK (250) = dedicated sweeper: wave 0 sweeps the 250 slots for each
// target 1..NBARS (s_sleep-paced) and publishes gen; waves 1..15 exit at
// start, leaving the CU idle. Workers: A hist -> B scans -> C scatter + inits
// -> 19-barrier loop. Pruning: edgeS keeps mask[src]!=0; edgeT keeps
// mask[src]!=0 && mask[tgt]!=0. 2 waves per active node, round-robin dealt.

template <bool L2M>
__global__ __launch_bounds__(1024, 4) void pc_all(
    const float* __restrict__ x, float* __restrict__ out,
    const int* __restrict__ src, const int* __restrict__ tgt,
    const float* __restrict__ w, const float* __restrict__ mask,
    int* __restrict__ partS, int* __restrict__ partT,
    int* __restrict__ offS, int* __restrict__ offT,
    int* __restrict__ curS, int* __restrict__ curT,
    int* __restrict__ actv, int* __restrict__ nactg,
    uint32_t* __restrict__ edgeS, uint32_t* __restrict__ edgeT,
    uint32_t* fx32, uint32_t* err32, uint32_t* barbuf, int E, int N) {
  __shared__ int h[4096];
  __shared__ uint32_t sE[2][16][CAP_H];
  __shared__ float2 psum[8][64];
  uint32_t* slots = barbuf;
  uint32_t* gen = barbuf + 288;

  const int bid = blockIdx.x, tid = threadIdx.x;
  const int wid = tid >> 6, lane = tid & 63;

  // ---- dedicated sweeper block: private loop, no __syncthreads, then exit ----
  if (bid == WRK) {
    if (wid == 0) {
      for (uint32_t t = 1; t <= (uint32_t)NBARS; ++t) {
        for (;;) {
          bool ok = true;
          for (int i = lane; i < WRK; i += 64) ok &= (aload(&slots[i]) >= t);
          if (__all(ok)) break;
          __builtin_amdgcn_s_sleep(1);
        }
        if (lane == 0) astore(gen, t);
      }
    }
    return;
  }

  const int row = N * 64;
  const int fstr = L2M ? row : 0;
  const int estr = L2M ? row : 0;

  // ---- A: pruned partial histograms ----
  if (bid < HB) {
    for (int i = tid; i < 2 * N; i += 1024) h[i] = 0;
    __syncthreads();
    const int chunk = (E + HB - 1) / HB;
    const int base = bid * chunk;
    const int end = min(base + chunk, E);
    for (int e = base + tid; e < end; e += 1024) {
      int s = src[e], t = tgt[e];
      if (mask[s] != 0.f) {
        atomicAdd(&h[s], 1);
        if (mask[t] != 0.f) atomicAdd(&h[N + t], 1);
      }
    }
    __syncthreads();
    for (int i = tid; i < N; i += 1024) {
      astore((uint32_t*)&partS[bid * 2048 + i], (uint32_t)h[i]);
      astore((uint32_t*)&partT[bid * 2048 + i], (uint32_t)h[N + i]);
    }
  }
  gbar(slots, gen, 1);

  // ---- B: exclusive scans (block 0 -> S, 1 -> T, 2 -> active compaction) ----
  if (bid < 3) {
    int* tsum = h;
    int v2[2];
    int s = 0;
#pragma unroll
    for (int i2 = 0; i2 < 2; ++i2) {
      int idx = tid * 2 + i2;
      int c = 0;
      if (idx < N) {
        if (bid == 2) {
          c = (mask[idx] != 0.f) ? 1 : 0;
        } else {
          const uint32_t* part = (const uint32_t*)(bid ? partT : partS);
          for (int k = 0; k < HB; ++k) c += (int)aload(&part[k * 2048 + idx]);
        }
      }
      v2[i2] = s;
      s += c;
    }
    __syncthreads();
    tsum[tid] = s;
    __syncthreads();
    for (int d = 1; d < 1024; d <<= 1) {
      int t = (tid >= d) ? tsum[tid - d] : 0;
      __syncthreads();
      tsum[tid] += t;
      __syncthreads();
    }
    int tbase = tsum[tid] - s;
    if (bid == 2) {
#pragma unroll
      for (int i2 = 0; i2 < 2; ++i2) {
        int idx = tid * 2 + i2;
        if (idx < N && mask[idx] != 0.f)
          astore((uint32_t*)&actv[tbase + v2[i2]], (uint32_t)idx);
      }
      if (tid == 1023) astore((uint32_t*)nactg, (uint32_t)tsum[1023]);
    } else {
      int* off = bid ? offT : offS;
      int* cur = bid ? curT : curS;
#pragma unroll
      for (int i2 = 0; i2 < 2; ++i2) {
        int idx = tid * 2 + i2;
        if (idx < N) {
          int o = tbase + v2[i2];
          astore((uint32_t*)&off[idx], (uint32_t)o);
          astore((uint32_t*)&cur[idx], (uint32_t)o);
        } else if (idx == N) {
          astore((uint32_t*)&off[idx], (uint32_t)(tbase + v2[i2]));
        }
      }
    }
  }
  gbar(slots, gen, 2);

  // ---- C: pruned scatter + active setup + fx(0) + masked init ----
  {
    const int chunk = (E + WRK - 1) / WRK;
    const int base = bid * chunk;
    const int end = min(base + chunk, E);
    for (int e = base + tid; e < end; e += 1024) {
      int s = src[e], t = tgt[e];
      if (mask[s] != 0.f) {
        uint32_t wb = __float_as_uint(w[e]);
        wb = (wb + 0x7FFFu + ((wb >> 16) & 1u)) & 0xFFFF0000u;  // bf16 bits, high half
        int p = atomicAdd(&curS[s], 1);
        astore(&edgeS[p], (uint32_t)t | wb);  // mu pass: src gathers fx[tgt]
        if (mask[t] != 0.f) {
          int q = atomicAdd(&curT[t], 1);
          astore(&edgeT[q], (uint32_t)s | wb);  // agg pass: tgt gathers err[src]
        }
      }
    }
  }

  const int ps = wid >> 1, sub = wid & 1;
  const int nact = (int)aload((const uint32_t*)nactg);
  const int p = ps * WRK + bid;
  const bool act = (p < nact);
  int n = 0, i = 0, aS = 0, qlS = 0, qpS = 0, aT = 0, qlT = 0, qpT = 0;
  bool fS = true, fT = true;
  float m = 0.f, x0 = 0.f, x1 = 0.f, fx0 = 0.f, fx1 = 0.f, e0 = 0.f, e1 = 0.f;

  if (act) {
    n = (int)aload((const uint32_t*)&actv[p]);
    i = (n << 6) + lane;
    const uint32_t* offSu = (const uint32_t*)offS;
    const uint32_t* offTu = (const uint32_t*)offT;
    const int s0 = (int)aload(&offSu[n]), degS = (int)aload(&offSu[n + 1]) - s0;
    const int t0 = (int)aload(&offTu[n]), degT = (int)aload(&offTu[n + 1]) - t0;
    aS = s0 + ((degS * sub) >> 1); qlS = (s0 + ((degS * (sub + 1)) >> 1)) - aS;
    aT = t0 + ((degT * sub) >> 1); qlT = (t0 + ((degT * (sub + 1)) >> 1)) - aT;
    qpS = (qlS + 7) & ~7; qpT = (qlT + 7) & ~7;
    fS = (qpS <= CAP_H); fT = (qpT <= CAP_H);
    if (sub == 0) {  // primary owns node state; lane l owns batch (2l, 2l+1)
      m = mask[n];
      x0 = x[(2 * lane) * N + n];
      x1 = x[(2 * lane + 1) * N + n];
      fx0 = tanhf(x0);
      fx1 = tanhf(x1);
      astore(&fx32[i], pack_bf16x2(fx0, fx1));  // F_0
    }
  }
  // masked nodes: constant fx -> every F_k buffer; x never changes -> out = x
  for (int g = bid * 1024 + tid; g < row; g += WRK * 1024) {
    int nn = g >> 6;
    if (mask[nn] == 0.f) {
      int l = g & 63;
      uint32_t pv = pack_bf16x2(tanhf(x[(2 * l) * N + nn]), tanhf(x[(2 * l + 1) * N + nn]));
      if constexpr (L2M) {
        for (int k = 0; k < NITER; ++k) astore(&fx32[(size_t)k * row + g], pv);
      } else {
        astore(&fx32[g], pv);
      }
    }
  }
  for (int g = bid * 1024 + tid; g < N * 128; g += WRK * 1024) {
    int b = g / N, nn = g - b * N;
    if (mask[nn] == 0.f) out[g] = x[g];
  }
  gbar(slots, gen, 3);

  // ---- stage this wave's half-slices into LDS (wave-private) ----
  if (act) {
    if (fS)
      for (int k = lane; k < qpS; k += 64) sE[0][wid][k] = (k < qlS) ? aload(&edgeS[aS + k]) : 0u;
    if (fT)
      for (int k = lane; k < qpT; k += 64) sE[1][wid][k] = (k < qlT) ? aload(&edgeT[aT + k]) : 0u;
  }

  // ---- main loop ----
  uint32_t g = 3;
  for (int it = 0; it < NITER; ++it) {
    const uint32_t* Fk = fx32 + (size_t)it * fstr;
    uint32_t* Ek = err32 + (size_t)it * estr;
    // phase 1: mu half-gather over F_it; combine; publish E_it
    float p0 = 0.f, p1 = 0.f;
    if (act) {
      if (fS) gq_lds<L2M>(&sE[0][wid][0], qpS, Fk, lane, p0, p1);
      else    gq_glb<L2M>(edgeS + aS, qlS, Fk, lane, p0, p1);
      if (sub) psum[ps][lane] = make_float2(p0, p1);
    }
    __syncthreads();
    if (act && sub == 0) {
      float2 q = psum[ps][lane];
      e0 = (x0 - (p0 + q.x)) * m;
      e1 = (x1 - (p1 + q.y)) * m;
      astore(&Ek[i], pack_bf16x2(e0, e1));
    }
    gbar(slots, gen, ++g);

    // phase 2: agg half-gather over E_it; combine; update x; publish F_{it+1}
    if (act) {
      if (fT) gq_lds<L2M>(&sE[1][wid][0], qpT, Ek, lane, p0, p1);
      else    gq_glb<L2M>(edgeT + aT, qlT, Ek, lane, p0, p1);
      if (sub) psum[ps][lane] = make_float2(p0, p1);
    }
    __syncthreads();
    if (act && sub == 0) {
      float2 q = psum[ps][lane];
      const float ag0 = p0 + q.x, ag1 = p1 + q.y;
      const float dx0 = e0 - (1.f - fx0 * fx0) * ag0;
      const float dx1 = e1 - (1.f - fx1 * fx1) * ag1;
      x0 -= 0.5f * dx0 * m;
      x1 -= 0.5f * dx1 * m;
      fx0 = tanhf(x0);
      fx1 = tanhf(x1);
      if (it < NITER - 1) astore(&fx32[(size_t)(it + 1) * fstr + i], pack_bf16x2(fx0, fx1));
    }
    if (it < NITER - 1) gbar(slots, gen, ++g);
  }

  if (act && sub == 0) {
    out[(2 * lane) * N + n] = x0;
    out[(2 * lane + 1) * N + n] = x1;
  }
}

// ---------------- host ----------------

extern "C" void kernel_launch(void* const* d_in, const int* in_sizes, int n_in,
                              void* d_out, int out_size, void* d_ws, size_t ws_size,
                              hipStream_t stream) {
  const float* x = (const float*)d_in[0];
  const int* ei = (const int*)d_in[1];
  const float* w = (const float*)d_in[2];
  const float* mask = (const float*)d_in[3];
  int E = in_sizes[2];  // 131072
  int N = in_sizes[3];  // 2000
  const int* src = ei;
  const int* tgt = ei + E;
  float* out = (float*)d_out;

  size_t off = 0;
  auto alloc = [&](size_t bytes) -> void* {
    off = (off + 255) & ~(size_t)255;
    void* p = (char*)d_ws + off;
    off += bytes;
    return p;
  };
  uint32_t* edgeS = (uint32_t*)alloc((size_t)E * 4);
  uint32_t* edgeT = (uint32_t*)alloc((size_t)E * 4);
  int* partS = (int*)alloc((size_t)HB * 2048 * 4);
  int* partT = (int*)alloc((size_t)HB * 2048 * 4);
  int* offS = (int*)alloc(2048 * 4);
  int* offT = (int*)alloc(2048 * 4);
  int* curS = (int*)alloc(2048 * 4);
  int* curT = (int*)alloc(2048 * 4);
  int* actv = (int*)alloc(2048 * 4);
  int* nactg = (int*)alloc(64 * 4);
  uint32_t* barbuf = (uint32_t*)alloc(512 * 4);

  const size_t row = (size_t)N * 64 * 4;  // bytes per message buffer
  bool l2mode = (off + 2 * (size_t)NITER * row + 512) <= ws_size;
  uint32_t* fx32, *err32;
  if (l2mode) {
    fx32 = (uint32_t*)alloc((size_t)NITER * row);
    err32 = (uint32_t*)alloc((size_t)NITER * row);
  } else {
    fx32 = (uint32_t*)alloc(row);
    err32 = (uint32_t*)alloc(row);
  }

  // barrier state must be zero at the start of every replay (monotonic targets)
  hipMemsetAsync(barbuf, 0, 512 * 4, stream);

  if (l2mode) {
    pc_all<true><<<GRID, 1024, 0, stream>>>(x, out, src, tgt, w, mask, partS, partT, offS, offT,
                                            curS, curT, actv, nactg, edgeS, edgeT, fx32, err32,
                                            barbuf, E, N);
  } else {
    pc_all<false><<<GRID, 1024, 0, stream>>>(x, out, src, tgt, w, mask, partS, partT, offS, offT,
                                             curS, curT, actv, nactg, edgeS, edgeT, fx32, err32,
                                             barbuf, E, N);
  }
}